// Round 1
// baseline (421.827 us; speedup 1.0000x reference)
//
#include <hip/hip_runtime.h>
#include <hip/hip_bf16.h>

// Problem dims (fixed by setup_inputs)
#define B_   4
#define T_   4096
#define D_   512
#define E_   2048          // D_inner
#define M_   (B_*T_)       // 16384 rows
#define N1_  (2*E_)        // 4096 (interleaved hidden/gate cols)
#define K1_  D_            // 512
#define N2_  D_            // 512
#define K2_  E_            // 2048
#define CT_  128           // scan chunk length
#define NC_  (T_/CT_)      // 32 chunks

typedef __attribute__((ext_vector_type(8))) short short8_t;
typedef __attribute__((ext_vector_type(4))) float f32x4;

__device__ inline unsigned short f2bf(float f){
  unsigned u = __float_as_uint(f);
  u += 0x7fffu + ((u >> 16) & 1u);      // RNE
  return (unsigned short)(u >> 16);
}
__device__ inline float bf2f(unsigned h){ return __uint_as_float(h << 16); }

// ---------------------------------------------------------------- converts
__global__ __launch_bounds__(256) void conv_f32_bf16_x4(const float* __restrict__ in,
                                                        short* __restrict__ out, int n4){
  int i = blockIdx.x * 256 + threadIdx.x;
  if (i >= n4) return;
  float4 v = ((const float4*)in)[i];
  short4 o;
  o.x = (short)f2bf(v.x); o.y = (short)f2bf(v.y);
  o.z = (short)f2bf(v.z); o.w = (short)f2bf(v.w);
  ((short4*)out)[i] = o;
}

// W_hg [4096,512] -> Wp interleaved: row 2e = hidden row e, row 2e+1 = gate row e+2048
__global__ __launch_bounds__(128) void conv_whg(const float* __restrict__ W,
                                                short* __restrict__ Wp){
  int r = blockIdx.x;                                  // 0..4095
  int orig = (r & 1) ? (E_ + (r >> 1)) : (r >> 1);
  float4 v = ((const float4*)(W + (size_t)orig * K1_))[threadIdx.x];
  short4 o;
  o.x = (short)f2bf(v.x); o.y = (short)f2bf(v.y);
  o.z = (short)f2bf(v.z); o.w = (short)f2bf(v.w);
  ((short4*)(Wp + (size_t)r * K1_))[threadIdx.x] = o;
}

// ---------------------------------------------------------------- GEMM (B^T layout)
// EPI=0: epilogue computes a=sigmoid(-gate), b=sigmoid(gate)*g(hidden), packs 2xbf16
// EPI=1: plain f32 store + bias
template<int EPI>
__global__ __launch_bounds__(256)
void gemm_bt(const short* __restrict__ A, const short* __restrict__ Bmat, int K,
             const float* __restrict__ bias,
             unsigned* __restrict__ ab_out,
             float* __restrict__ c_out, int ldc)
{
  __shared__ short As[128 * 64];
  __shared__ short Bs[128 * 64];
  const int tid  = threadIdx.x;
  const int lane = tid & 63;
  const int w    = tid >> 6;
  const int wr   = (w >> 1) * 64;
  const int wc   = (w & 1) * 64;
  const int brow = blockIdx.y * 128;
  const int bcol = blockIdx.x * 128;

  f32x4 acc[4][4];
  #pragma unroll
  for (int m = 0; m < 4; ++m)
    #pragma unroll
    for (int n = 0; n < 4; ++n) acc[m][n] = (f32x4){0.f, 0.f, 0.f, 0.f};

  const int srow = lane >> 3;
  const int scol = (lane & 7) * 8;
  const int l15  = lane & 15;
  const int kh   = (lane >> 4) * 8;

  for (int kt = 0; kt < K; kt += 64) {
    #pragma unroll
    for (int i = 0; i < 4; ++i) {
      const int rr = (w * 4 + i) * 8 + srow;
      const short* ga = A    + (size_t)(brow + rr) * K + kt + scol;
      const short* gb = Bmat + (size_t)(bcol + rr) * K + kt + scol;
      __builtin_amdgcn_global_load_lds((const __attribute__((address_space(1))) void*)ga,
                                       (__attribute__((address_space(3))) void*)(As + (w * 4 + i) * 512),
                                       16, 0, 0);
      __builtin_amdgcn_global_load_lds((const __attribute__((address_space(1))) void*)gb,
                                       (__attribute__((address_space(3))) void*)(Bs + (w * 4 + i) * 512),
                                       16, 0, 0);
    }
    __syncthreads();
    #pragma unroll
    for (int kk = 0; kk < 64; kk += 32) {
      short8_t af[4], bf[4];
      #pragma unroll
      for (int m = 0; m < 4; ++m)
        af[m] = *(const short8_t*)(As + (wr + m * 16 + l15) * 64 + kk + kh);
      #pragma unroll
      for (int n = 0; n < 4; ++n)
        bf[n] = *(const short8_t*)(Bs + (wc + n * 16 + l15) * 64 + kk + kh);
      #pragma unroll
      for (int m = 0; m < 4; ++m)
        #pragma unroll
        for (int n = 0; n < 4; ++n)
          acc[m][n] = __builtin_amdgcn_mfma_f32_16x16x32_bf16(af[m], bf[n], acc[m][n], 0, 0, 0);
    }
    __syncthreads();
  }

  const int r4 = (lane >> 4) * 4;
  #pragma unroll
  for (int m = 0; m < 4; ++m) {
    #pragma unroll
    for (int n = 0; n < 4; ++n) {
      const int row = brow + wr + m * 16 + r4;
      const int col = bcol + wc + n * 16 + l15;
      if constexpr (EPI == 0) {
        const int e = col >> 1;
        const float bias_v = bias[(col & 1) ? (E_ + e) : e];
        #pragma unroll
        for (int j = 0; j < 4; ++j) {
          float v = acc[m][n][j] + bias_v;
          float p = __shfl_xor(v, 1, 64);
          float hh = (col & 1) ? p : v;   // hidden pre-activation
          float gg = (col & 1) ? v : p;   // gate pre-activation
          // stable sigmoid pair: z = sigmoid(gg), a = sigmoid(-gg)
          float mabs = fabsf(gg);
          float em   = __expf(-mabs);
          float inv  = 1.f / (1.f + em);
          float sp   = inv;          // sigmoid(|gg|)
          float sn   = em * inv;     // sigmoid(-|gg|)
          float z = (gg >= 0.f) ? sp : sn;
          float a = (gg >= 0.f) ? sn : sp;
          float gf = (hh >= 0.f) ? (hh + 0.5f) : (1.f / (1.f + __expf(-hh)));
          float bb = z * gf;
          if (!(col & 1)) {
            unsigned pk = ((unsigned)f2bf(bb) << 16) | (unsigned)f2bf(a);
            ab_out[(size_t)(row + j) * E_ + e] = pk;
          }
        }
      } else {
        #pragma unroll
        for (int j = 0; j < 4; ++j)
          c_out[(size_t)(row + j) * ldc + col] = acc[m][n][j] + bias[col];
      }
    }
  }
}

// ---------------------------------------------------------------- scan (3-pass)
// Pass 1: per-chunk aggregates A = prod a, Bv = local recurrence from 0
__global__ __launch_bounds__(256) void scan_chunk(const unsigned* __restrict__ ab,
                                                  float* __restrict__ Ac,
                                                  float* __restrict__ Bc){
  const int c = blockIdx.x;
  const int e = blockIdx.y * 256 + threadIdx.x;
  const int b = blockIdx.z;
  size_t base = ((size_t)b * T_ + (size_t)c * CT_) * E_ + e;
  float A = 1.f, H = 0.f;
  #pragma unroll 8
  for (int t = 0; t < CT_; ++t) {
    unsigned wv = ab[base + (size_t)t * E_];
    float a  = bf2f(wv & 0xffffu);
    float bv = bf2f(wv >> 16);
    H = fmaf(a, H, bv);
    A *= a;
  }
  size_t ci = ((size_t)b * NC_ + c) * E_ + e;
  Ac[ci] = A; Bc[ci] = H;
}

// Pass 2: carry scan over chunks. NOTE: initial hidden state is 1.0 (the
// reference pads log_values with 0 -> value exp(0)=1 at t=-1).
__global__ __launch_bounds__(256) void scan_carry(const float* __restrict__ Ac,
                                                  const float* __restrict__ Bc,
                                                  float* __restrict__ Hc){
  int idx = blockIdx.x * 256 + threadIdx.x;   // 0..B_*E_-1
  int b = idx >> 11;                          // /E_
  int e = idx & (E_ - 1);
  float H = 1.f;                              // h_0 = 1 !
  for (int c = 0; c < NC_; ++c) {
    size_t ci = ((size_t)b * NC_ + c) * E_ + e;
    float A = Ac[ci], Bv = Bc[ci];
    Hc[ci] = H;                               // carry-in for chunk c
    H = fmaf(A, H, Bv);
  }
}

// Pass 3: replay with carry, write h as bf16
__global__ __launch_bounds__(256) void scan_final(const unsigned* __restrict__ ab,
                                                  const float* __restrict__ Hc,
                                                  short* __restrict__ h){
  const int c = blockIdx.x;
  const int e = blockIdx.y * 256 + threadIdx.x;
  const int b = blockIdx.z;
  size_t base = ((size_t)b * T_ + (size_t)c * CT_) * E_ + e;
  float H = Hc[((size_t)b * NC_ + c) * E_ + e];
  #pragma unroll 8
  for (int t = 0; t < CT_; ++t) {
    unsigned wv = ab[base + (size_t)t * E_];
    float a  = bf2f(wv & 0xffffu);
    float bv = bf2f(wv >> 16);
    H = fmaf(a, H, bv);
    h[base + (size_t)t * E_] = (short)f2bf(H);
  }
}

// ---------------------------------------------------------------- launch
extern "C" void kernel_launch(void* const* d_in, const int* in_sizes, int n_in,
                              void* d_out, int out_size, void* d_ws, size_t ws_size,
                              hipStream_t stream)
{
  const float* x     = (const float*)d_in[0];
  const float* W_hg  = (const float*)d_in[1];
  const float* b_hg  = (const float*)d_in[2];
  const float* W_out = (const float*)d_in[3];
  const float* b_out = (const float*)d_in[4];
  float* out = (float*)d_out;

  char* p = (char*)d_ws;
  auto carve = [&](size_t bytes) -> char* {
    char* q = p; p += (bytes + 255) & ~(size_t)255; return q;
  };
  short*    xb   = (short*)   carve((size_t)M_ * K1_ * 2);   // 16.8 MB
  short*    Wp   = (short*)   carve((size_t)N1_ * K1_ * 2);  //  4.2 MB
  short*    Wo   = (short*)   carve((size_t)N2_ * K2_ * 2);  //  2.1 MB
  unsigned* ab   = (unsigned*)carve((size_t)M_ * E_ * 4);    // 134.2 MB
  short*    hbuf = (short*)   carve((size_t)M_ * E_ * 2);    // 67.1 MB
  float*    Ac   = (float*)   carve((size_t)B_ * NC_ * E_ * 4);
  float*    Bc   = (float*)   carve((size_t)B_ * NC_ * E_ * 4);
  float*    Hc   = (float*)   carve((size_t)B_ * NC_ * E_ * 4);

  conv_f32_bf16_x4<<<(M_ * K1_ / 4 + 255) / 256, 256, 0, stream>>>(x, xb, M_ * K1_ / 4);
  conv_whg<<<N1_, 128, 0, stream>>>(W_hg, Wp);
  conv_f32_bf16_x4<<<(N2_ * K2_ / 4 + 255) / 256, 256, 0, stream>>>(W_out, Wo, N2_ * K2_ / 4);

  gemm_bt<0><<<dim3(N1_ / 128, M_ / 128), 256, 0, stream>>>(xb, Wp, K1_, b_hg, ab, nullptr, 0);

  scan_chunk<<<dim3(NC_, E_ / 256, B_), 256, 0, stream>>>(ab, Ac, Bc);
  scan_carry<<<(B_ * E_) / 256, 256, 0, stream>>>(Ac, Bc, Hc);
  scan_final<<<dim3(NC_, E_ / 256, B_), 256, 0, stream>>>(ab, Hc, hbuf);

  gemm_bt<1><<<dim3(N2_ / 128, M_ / 128), 256, 0, stream>>>(hbuf, Wo, K2_, b_out, nullptr, out, N2_);
}

// Round 2
// 304.273 us; speedup vs baseline: 1.3863x; 1.3863x over previous
//
#include <hip/hip_runtime.h>
#include <hip/hip_bf16.h>

// Problem dims (fixed by setup_inputs)
#define B_   4
#define T_   4096
#define D_   512
#define E_   2048          // D_inner
#define M_   (B_*T_)       // 16384 rows
#define N1_  (2*E_)        // 4096 (reordered hidden/gate cols)
#define K1_  D_            // 512
#define N2_  D_            // 512
#define K2_  E_            // 2048
#define CT_  128           // scan chunk length
#define NC_  (T_/CT_)      // 32 chunks

typedef __attribute__((ext_vector_type(8))) short short8_t;
typedef __attribute__((ext_vector_type(4))) float f32x4;

__device__ inline unsigned short f2bf(float f){
  unsigned u = __float_as_uint(f);
  u += 0x7fffu + ((u >> 16) & 1u);      // RNE
  return (unsigned short)(u >> 16);
}
__device__ inline float bf2f(unsigned h){ return __uint_as_float(h << 16); }

// ---------------------------------------------------------------- converts
__global__ __launch_bounds__(256) void conv_f32_bf16_x4(const float* __restrict__ in,
                                                        short* __restrict__ out, int n4){
  int i = blockIdx.x * 256 + threadIdx.x;
  if (i >= n4) return;
  float4 v = ((const float4*)in)[i];
  short4 o;
  o.x = (short)f2bf(v.x); o.y = (short)f2bf(v.y);
  o.z = (short)f2bf(v.z); o.w = (short)f2bf(v.w);
  ((short4*)out)[i] = o;
}

// W_hg [4096,512] -> Wp reordered: within each 64-col wave tile,
// cols 0..31 = hidden rows e_base..e_base+31, cols 32..63 = matching gate rows.
// r -> e = ((r>>6)<<5) + (r&31), is_gate = (r>>5)&1
__global__ __launch_bounds__(128) void conv_whg(const float* __restrict__ W,
                                                short* __restrict__ Wp){
  int r = blockIdx.x;                                  // 0..4095
  int e = ((r >> 6) << 5) + (r & 31);
  int orig = e + ((r >> 5) & 1) * E_;
  float4 v = ((const float4*)(W + (size_t)orig * K1_))[threadIdx.x];
  short4 o;
  o.x = (short)f2bf(v.x); o.y = (short)f2bf(v.y);
  o.z = (short)f2bf(v.z); o.w = (short)f2bf(v.w);
  ((short4*)(Wp + (size_t)r * K1_))[threadIdx.x] = o;
}

// ---------------------------------------------------------------- GEMM (B^T layout)
// LDS layout: linear rows of 64 shorts (128 B), XOR-swizzled st-16x32 style:
//   lds(row, colbyte) holds global(row, colbyte ^ ((row&7)<<4))
// achieved by pre-swizzling the GLOBAL source column of global_load_lds
// (linear LDS dest, rule: both-sides-or-neither) and XOR-ing the ds_read addr.
template<int EPI>
__global__ __launch_bounds__(256)
void gemm_bt(const short* __restrict__ A, const short* __restrict__ Bmat, int K,
             const float* __restrict__ bias,
             unsigned* __restrict__ ab_out,
             float* __restrict__ c_out, int ldc)
{
  __shared__ short As[128 * 64];
  __shared__ short Bs[128 * 64];
  const int tid  = threadIdx.x;
  const int lane = tid & 63;
  const int w    = tid >> 6;
  const int wr   = (w >> 1) * 64;
  const int wc   = (w & 1) * 64;

  // bijective XCD-aware block swizzle (grid % 8 == 0 for both GEMMs)
  const int nwg = gridDim.x * gridDim.y;
  const int lin = blockIdx.y * gridDim.x + blockIdx.x;
  const int nl  = (lin & 7) * (nwg >> 3) + (lin >> 3);
  const int brow = (nl / gridDim.x) * 128;
  const int bcol = (nl % gridDim.x) * 128;

  f32x4 acc[4][4];
  #pragma unroll
  for (int m = 0; m < 4; ++m)
    #pragma unroll
    for (int n = 0; n < 4; ++n) acc[m][n] = (f32x4){0.f, 0.f, 0.f, 0.f};

  const int srow = lane >> 3;
  const int scol = ((lane & 7) ^ srow) * 8;   // pre-swizzled global col (shorts)
  const int l15  = lane & 15;
  const int kh   = (lane >> 4) * 8;
  const int sw   = (l15 & 7) << 3;            // ds_read XOR (shorts)

  for (int kt = 0; kt < K; kt += 64) {
    #pragma unroll
    for (int i = 0; i < 4; ++i) {
      const int rr = (w * 4 + i) * 8 + srow;
      const short* ga = A    + (size_t)(brow + rr) * K + kt + scol;
      const short* gb = Bmat + (size_t)(bcol + rr) * K + kt + scol;
      __builtin_amdgcn_global_load_lds((const __attribute__((address_space(1))) void*)ga,
                                       (__attribute__((address_space(3))) void*)(As + (w * 4 + i) * 512),
                                       16, 0, 0);
      __builtin_amdgcn_global_load_lds((const __attribute__((address_space(1))) void*)gb,
                                       (__attribute__((address_space(3))) void*)(Bs + (w * 4 + i) * 512),
                                       16, 0, 0);
    }
    __syncthreads();
    #pragma unroll
    for (int kk = 0; kk < 64; kk += 32) {
      short8_t af[4], bf[4];
      #pragma unroll
      for (int m = 0; m < 4; ++m)
        af[m] = *(const short8_t*)(As + (wr + m * 16 + l15) * 64 + ((kk + kh) ^ sw));
      #pragma unroll
      for (int n = 0; n < 4; ++n)
        bf[n] = *(const short8_t*)(Bs + (wc + n * 16 + l15) * 64 + ((kk + kh) ^ sw));
      #pragma unroll
      for (int m = 0; m < 4; ++m)
        #pragma unroll
        for (int n = 0; n < 4; ++n)
          acc[m][n] = __builtin_amdgcn_mfma_f32_16x16x32_bf16(af[m], bf[n], acc[m][n], 0, 0, 0);
    }
    __syncthreads();
  }

  const int r4 = (lane >> 4) * 4;
  if constexpr (EPI == 0) {
    // cols [wc..wc+31] = hidden(e), [wc+32..wc+63] = gate(e): same lane holds both
    const int ebase = (bcol + wc) >> 1;
    #pragma unroll
    for (int m = 0; m < 4; ++m) {
      const int row = brow + wr + m * 16 + r4;
      #pragma unroll
      for (int n = 0; n < 2; ++n) {
        const int e = ebase + n * 16 + l15;
        const float bh = bias[e];
        const float bg = bias[E_ + e];
        #pragma unroll
        for (int j = 0; j < 4; ++j) {
          float hh = acc[m][n][j]     + bh;   // hidden pre-activation
          float gg = acc[m][n + 2][j] + bg;   // gate pre-activation
          float mabs = fabsf(gg);
          float em   = __expf(-mabs);
          float inv  = 1.f / (1.f + em);
          float z = (gg >= 0.f) ? inv : em * inv;       // sigmoid(gg)
          float a = (gg >= 0.f) ? em * inv : inv;       // sigmoid(-gg)
          float gf = (hh >= 0.f) ? (hh + 0.5f) : (1.f / (1.f + __expf(-hh)));
          float bb = z * gf;
          unsigned pk = ((unsigned)f2bf(bb) << 16) | (unsigned)f2bf(a);
          ab_out[(size_t)(row + j) * E_ + e] = pk;
        }
      }
    }
  } else {
    #pragma unroll
    for (int m = 0; m < 4; ++m) {
      #pragma unroll
      for (int n = 0; n < 4; ++n) {
        const int row = brow + wr + m * 16 + r4;
        const int col = bcol + wc + n * 16 + l15;
        #pragma unroll
        for (int j = 0; j < 4; ++j)
          c_out[(size_t)(row + j) * ldc + col] = acc[m][n][j] + bias[col];
      }
    }
  }
}

// ---------------------------------------------------------------- scan (3-pass)
// Pass 1: per-chunk aggregates A = prod a, Bv = local recurrence from 0.
// Each thread handles 4 adjacent channels (16 B/lane loads).
__global__ __launch_bounds__(256) void scan_chunk(const unsigned* __restrict__ ab,
                                                  float* __restrict__ Ac,
                                                  float* __restrict__ Bc){
  const int c = blockIdx.x;
  const int e = (blockIdx.y * 256 + threadIdx.x) * 4;
  const int b = blockIdx.z;
  size_t base = (((size_t)b * T_ + (size_t)c * CT_) * E_ + e) >> 2;  // uint4 index
  const uint4* abv = (const uint4*)ab;
  float A0=1.f,A1=1.f,A2=1.f,A3=1.f, H0=0.f,H1=0.f,H2=0.f,H3=0.f;
  #pragma unroll 4
  for (int t = 0; t < CT_; ++t) {
    uint4 wv = abv[base + (size_t)t * (E_ / 4)];
    float a0=bf2f(wv.x&0xffffu), b0=bf2f(wv.x>>16);
    float a1=bf2f(wv.y&0xffffu), b1=bf2f(wv.y>>16);
    float a2=bf2f(wv.z&0xffffu), b2=bf2f(wv.z>>16);
    float a3=bf2f(wv.w&0xffffu), b3=bf2f(wv.w>>16);
    H0=fmaf(a0,H0,b0); H1=fmaf(a1,H1,b1); H2=fmaf(a2,H2,b2); H3=fmaf(a3,H3,b3);
    A0*=a0; A1*=a1; A2*=a2; A3*=a3;
  }
  size_t ci = (((size_t)b * NC_ + c) * E_ + e) >> 2;
  ((float4*)Ac)[ci] = (float4){A0,A1,A2,A3};
  ((float4*)Bc)[ci] = (float4){H0,H1,H2,H3};
}

// Pass 2: carry scan over chunks. Initial hidden state is 1.0 (the reference
// pads log_values with 0 -> value exp(0)=1 at t=-1).
__global__ __launch_bounds__(256) void scan_carry(const float* __restrict__ Ac,
                                                  const float* __restrict__ Bc,
                                                  float* __restrict__ Hc){
  int idx = blockIdx.x * 256 + threadIdx.x;   // 0..B_*E_-1
  int b = idx >> 11;                          // /E_
  int e = idx & (E_ - 1);
  float H = 1.f;                              // h_0 = 1 !
  for (int c = 0; c < NC_; ++c) {
    size_t ci = ((size_t)b * NC_ + c) * E_ + e;
    float A = Ac[ci], Bv = Bc[ci];
    Hc[ci] = H;                               // carry-in for chunk c
    H = fmaf(A, H, Bv);
  }
}

// Pass 3: replay with carry, write h as bf16 (4 channels/thread, 8B stores)
__global__ __launch_bounds__(256) void scan_final(const unsigned* __restrict__ ab,
                                                  const float* __restrict__ Hc,
                                                  short* __restrict__ h){
  const int c = blockIdx.x;
  const int e = (blockIdx.y * 256 + threadIdx.x) * 4;
  const int b = blockIdx.z;
  size_t base = (((size_t)b * T_ + (size_t)c * CT_) * E_ + e) >> 2;
  const uint4* abv = (const uint4*)ab;
  float4 Hv = ((const float4*)Hc)[(((size_t)b * NC_ + c) * E_ + e) >> 2];
  float H0=Hv.x, H1=Hv.y, H2=Hv.z, H3=Hv.w;
  short4* hv = (short4*)h;
  #pragma unroll 4
  for (int t = 0; t < CT_; ++t) {
    uint4 wv = abv[base + (size_t)t * (E_ / 4)];
    H0 = fmaf(bf2f(wv.x&0xffffu), H0, bf2f(wv.x>>16));
    H1 = fmaf(bf2f(wv.y&0xffffu), H1, bf2f(wv.y>>16));
    H2 = fmaf(bf2f(wv.z&0xffffu), H2, bf2f(wv.z>>16));
    H3 = fmaf(bf2f(wv.w&0xffffu), H3, bf2f(wv.w>>16));
    short4 o;
    o.x=(short)f2bf(H0); o.y=(short)f2bf(H1); o.z=(short)f2bf(H2); o.w=(short)f2bf(H3);
    hv[base + (size_t)t * (E_ / 4)] = o;
  }
}

// ---------------------------------------------------------------- launch
extern "C" void kernel_launch(void* const* d_in, const int* in_sizes, int n_in,
                              void* d_out, int out_size, void* d_ws, size_t ws_size,
                              hipStream_t stream)
{
  const float* x     = (const float*)d_in[0];
  const float* W_hg  = (const float*)d_in[1];
  const float* b_hg  = (const float*)d_in[2];
  const float* W_out = (const float*)d_in[3];
  const float* b_out = (const float*)d_in[4];
  float* out = (float*)d_out;

  char* p = (char*)d_ws;
  auto carve = [&](size_t bytes) -> char* {
    char* q = p; p += (bytes + 255) & ~(size_t)255; return q;
  };
  short*    xb   = (short*)   carve((size_t)M_ * K1_ * 2);   // 16.8 MB
  short*    Wp   = (short*)   carve((size_t)N1_ * K1_ * 2);  //  4.2 MB
  short*    Wo   = (short*)   carve((size_t)N2_ * K2_ * 2);  //  2.1 MB
  unsigned* ab   = (unsigned*)carve((size_t)M_ * E_ * 4);    // 134.2 MB
  short*    hbuf = (short*)   carve((size_t)M_ * E_ * 2);    // 67.1 MB
  float*    Ac   = (float*)   carve((size_t)B_ * NC_ * E_ * 4);
  float*    Bc   = (float*)   carve((size_t)B_ * NC_ * E_ * 4);
  float*    Hc   = (float*)   carve((size_t)B_ * NC_ * E_ * 4);

  conv_f32_bf16_x4<<<(M_ * K1_ / 4 + 255) / 256, 256, 0, stream>>>(x, xb, M_ * K1_ / 4);
  conv_whg<<<N1_, 128, 0, stream>>>(W_hg, Wp);
  conv_f32_bf16_x4<<<(N2_ * K2_ / 4 + 255) / 256, 256, 0, stream>>>(W_out, Wo, N2_ * K2_ / 4);

  gemm_bt<0><<<dim3(N1_ / 128, M_ / 128), 256, 0, stream>>>(xb, Wp, K1_, b_hg, ab, nullptr, 0);

  scan_chunk<<<dim3(NC_, E_ / 1024, B_), 256, 0, stream>>>(ab, Ac, Bc);
  scan_carry<<<(B_ * E_) / 256, 256, 0, stream>>>(Ac, Bc, Hc);
  scan_final<<<dim3(NC_, E_ / 1024, B_), 256, 0, stream>>>(ab, Hc, hbuf);

  gemm_bt<1><<<dim3(N2_ / 128, M_ / 128), 256, 0, stream>>>(hbuf, Wo, K2_, b_out, nullptr, out, N2_);
}

// Round 3
// 301.083 us; speedup vs baseline: 1.4010x; 1.0106x over previous
//
#include <hip/hip_runtime.h>
#include <hip/hip_bf16.h>

// Problem dims (fixed by setup_inputs)
#define B_   4
#define T_   4096
#define D_   512
#define E_   2048          // D_inner
#define M_   (B_*T_)       // 16384 rows
#define N1_  (2*E_)        // 4096 (reordered hidden/gate cols)
#define K1_  D_            // 512
#define N2_  D_            // 512
#define K2_  E_            // 2048
#define CT_  128           // scan chunk length
#define NC_  (T_/CT_)      // 32 chunks

typedef __attribute__((ext_vector_type(8))) short short8_t;
typedef __attribute__((ext_vector_type(4))) float f32x4;

__device__ inline unsigned short f2bf(float f){
  unsigned u = __float_as_uint(f);
  u += 0x7fffu + ((u >> 16) & 1u);      // RNE
  return (unsigned short)(u >> 16);
}
__device__ inline float bf2f(unsigned h){ return __uint_as_float(h << 16); }

#define STG(gp, lp) __builtin_amdgcn_global_load_lds( \
    (const __attribute__((address_space(1))) void*)(gp), \
    (__attribute__((address_space(3))) void*)(lp), 16, 0, 0)
#define BAR()   __builtin_amdgcn_s_barrier()
#define LGKM0() asm volatile("s_waitcnt lgkmcnt(0)" ::: "memory")
#define VM4()   asm volatile("s_waitcnt vmcnt(4)" ::: "memory")
#define VM0()   asm volatile("s_waitcnt vmcnt(0)" ::: "memory")
#define PRIO1() __builtin_amdgcn_s_setprio(1)
#define PRIO0() __builtin_amdgcn_s_setprio(0)

// ---------------------------------------------------------------- converts
__global__ __launch_bounds__(256) void conv_f32_bf16_x4(const float* __restrict__ in,
                                                        short* __restrict__ out, int n4){
  int i = blockIdx.x * 256 + threadIdx.x;
  if (i >= n4) return;
  float4 v = ((const float4*)in)[i];
  short4 o;
  o.x = (short)f2bf(v.x); o.y = (short)f2bf(v.y);
  o.z = (short)f2bf(v.z); o.w = (short)f2bf(v.w);
  ((short4*)out)[i] = o;
}

// W_hg [4096,512] -> Wp reordered: within each 64-col wave tile,
// cols 0..31 = hidden rows e_base..e_base+31, cols 32..63 = matching gate rows.
__global__ __launch_bounds__(128) void conv_whg(const float* __restrict__ W,
                                                short* __restrict__ Wp){
  int r = blockIdx.x;                                  // 0..4095
  int e = ((r >> 6) << 5) + (r & 31);
  int orig = e + ((r >> 5) & 1) * E_;
  float4 v = ((const float4*)(W + (size_t)orig * K1_))[threadIdx.x];
  short4 o;
  o.x = (short)f2bf(v.x); o.y = (short)f2bf(v.y);
  o.z = (short)f2bf(v.z); o.w = (short)f2bf(v.w);
  ((short4*)(Wp + (size_t)r * K1_))[threadIdx.x] = o;
}

// ---------------------------------------------------------------- GEMM1: 256x256, 8-phase
// BM=BN=256, BK=64, 8 waves (2M x 4N), per-wave 128x64 output.
// LDS: As[2][256][64], Bs[2][256][64] shorts = 128 KiB, XOR-swizzled
// (colbyte ^= (row&7)<<4) via pre-swizzled global src + swizzled ds_read.
// Schedule (derived, race-free; barriers separate all stage-vs-read pairs):
//   buf0 = even K-tiles, buf1 = odd. Iter j computes KT_{2j} (ph1-4, buf0)
//   then KT_{2j+1} (ph5-8, buf1).
//   stages: ph1,2 -> buf1 A (KT_{2j+1}); ph3,4 -> buf0 B (KT_{2j+2});
//           ph5,6 -> buf0 A (KT_{2j+2}); ph7,8 -> buf1 B (KT_{2j+3}).
//   vmcnt(4) at ph4 lands KT_{2j+1} (B staged prev ph7,8 + A ph1,2) before ph5
//   reads; vmcnt(4) at ph8 lands KT_{2j+2} before next ph1. 2 half-tiles stay
//   in flight. ds-read retirement: A-half read ph1,3 (staged ph5,6: safe);
//   B-half read ph1,2 (staged ph3,4: safe).
template<int KK>
__global__ __launch_bounds__(512, 2)
void gemm8p_ab(const short* __restrict__ A, const short* __restrict__ Bmat,
               const float* __restrict__ bias, unsigned* __restrict__ ab_out)
{
  __shared__ short As[2][256 * 64];
  __shared__ short Bs[2][256 * 64];
  constexpr int NT = KK / 64, NI = NT / 2;

  const int tid = threadIdx.x;
  const int lane = tid & 63;
  const int w   = tid >> 6;      // 0..7
  const int wm  = w >> 2;        // 0..1 (row half)
  const int wn  = w & 3;         // 0..3 (64-col slice)
  const int l15 = lane & 15;
  const int kh  = (lane >> 4) * 8;
  const int swz = (l15 & 7) << 3;

  // bijective XCD swizzle (nwg % 8 == 0)
  const int nwg = gridDim.x * gridDim.y;
  const int lin = blockIdx.y * gridDim.x + blockIdx.x;
  const int nl  = (lin & 7) * (nwg >> 3) + (lin >> 3);
  const int brow = (nl / gridDim.x) * 256;
  const int bcol = (nl % gridDim.x) * 256;

  // staging addresses: wave w stages rows [w*16, w*16+16) of each 128-row half
  const int srow8 = lane >> 3;                 // 0..7
  const int scol  = ((lane & 7) ^ srow8) * 8;  // pre-swizzled global col (shorts)
  const short *gA0[2], *gA1[2], *gB0[2], *gB1[2];
  #pragma unroll
  for (int h = 0; h < 2; ++h) {
    gA0[h] = A    + (size_t)(brow + h * 128 + w * 16 + srow8) * KK + scol;
    gA1[h] = gA0[h] + 8 * KK;
    gB0[h] = Bmat + (size_t)(bcol + h * 128 + w * 16 + srow8) * KK + scol;
    gB1[h] = gB0[h] + 8 * KK;
  }
  auto stgA = [&](int db, int h, int kt) {
    STG(gA0[h] + kt, &As[db][(h * 128 + w * 16) * 64]);
    STG(gA1[h] + kt, &As[db][(h * 128 + w * 16 + 8) * 64]);
  };
  auto stgB = [&](int db, int h, int kt) {
    STG(gB0[h] + kt, &Bs[db][(h * 128 + w * 16) * 64]);
    STG(gB1[h] + kt, &Bs[db][(h * 128 + w * 16 + 8) * 64]);
  };

  f32x4 acc[8][4];
  #pragma unroll
  for (int m = 0; m < 8; ++m)
    #pragma unroll
    for (int n = 0; n < 4; ++n) acc[m][n] = (f32x4){0.f, 0.f, 0.f, 0.f};

  short8_t af[4][2], bf[4][2];
  auto LDA4 = [&](int db, int qr) {
    #pragma unroll
    for (int i = 0; i < 4; ++i) {
      const int rb = (wm * 128 + qr * 64 + i * 16 + l15) * 64;
      af[i][0] = *(const short8_t*)&As[db][rb + (kh ^ swz)];
      af[i][1] = *(const short8_t*)&As[db][rb + ((32 + kh) ^ swz)];
    }
  };
  auto LDB2 = [&](int db, int hf) {
    #pragma unroll
    for (int n = 0; n < 2; ++n) {
      const int rb = (wn * 64 + (hf * 2 + n) * 16 + l15) * 64;
      bf[hf * 2 + n][0] = *(const short8_t*)&Bs[db][rb + (kh ^ swz)];
      bf[hf * 2 + n][1] = *(const short8_t*)&Bs[db][rb + ((32 + kh) ^ swz)];
    }
  };
  auto QUAD = [&](int ar, int bn) {
    #pragma unroll
    for (int kk = 0; kk < 2; ++kk)
      #pragma unroll
      for (int i = 0; i < 4; ++i)
        #pragma unroll
        for (int n = 0; n < 2; ++n)
          acc[ar + i][bn + n] = __builtin_amdgcn_mfma_f32_16x16x32_bf16(
              af[i][kk], bf[bn + n][kk], acc[ar + i][bn + n], 0, 0, 0);
  };

  // prologue: KT0 full (A h0,h1, B h0,h1) + KT1 B h0,h1; land KT0, keep KT1-B in flight
  stgA(0, 0, 0); stgA(0, 1, 0); stgB(0, 0, 0); stgB(0, 1, 0);
  stgB(1, 0, 64); stgB(1, 1, 64);
  VM4(); BAR();

  for (int j = 0; j < NI; ++j) {
    const bool last = (j == NI - 1);
    const int ktB1 = (2 * j + 1) * 64;
    const int ktN0 = (2 * j + 2) * 64;
    const int ktN1 = (2 * j + 3) * 64;
    // P1
    LDA4(0, 0); LDB2(0, 0); stgA(1, 0, ktB1);
    BAR(); LGKM0(); PRIO1(); QUAD(0, 0); PRIO0(); BAR();
    // P2
    LDB2(0, 1); stgA(1, 1, ktB1);
    BAR(); LGKM0(); PRIO1(); QUAD(0, 2); PRIO0(); BAR();
    // P3
    LDA4(0, 1); if (!last) stgB(0, 0, ktN0);
    BAR(); LGKM0(); PRIO1(); QUAD(4, 0); PRIO0(); BAR();
    // P4
    if (!last) stgB(0, 1, ktN0);
    BAR(); LGKM0(); PRIO1(); QUAD(4, 2); PRIO0();
    if (last) { VM0(); } else { VM4(); }
    BAR();
    // P5
    LDA4(1, 0); LDB2(1, 0); if (!last) stgA(0, 0, ktN0);
    BAR(); LGKM0(); PRIO1(); QUAD(0, 0); PRIO0(); BAR();
    // P6
    LDB2(1, 1); if (!last) stgA(0, 1, ktN0);
    BAR(); LGKM0(); PRIO1(); QUAD(0, 2); PRIO0(); BAR();
    // P7
    LDA4(1, 1); if (!last) stgB(1, 0, ktN1);
    BAR(); LGKM0(); PRIO1(); QUAD(4, 0); PRIO0(); BAR();
    // P8
    if (!last) stgB(1, 1, ktN1);
    BAR(); LGKM0(); PRIO1(); QUAD(4, 2); PRIO0();
    if (!last) { VM4(); }
    BAR();
  }

  // epilogue: a = sigmoid(-gate), b = sigmoid(gate)*g(hidden), pack 2xbf16
  const int r4 = (lane >> 4) * 4;
  const int ebase = (bcol + wn * 64) >> 1;
  #pragma unroll
  for (int ar = 0; ar < 8; ++ar) {
    const int row = brow + wm * 128 + ar * 16 + r4;
    #pragma unroll
    for (int bn = 0; bn < 2; ++bn) {
      const int e = ebase + bn * 16 + l15;
      const float bh = bias[e];
      const float bg = bias[E_ + e];
      #pragma unroll
      for (int jj = 0; jj < 4; ++jj) {
        float hh = acc[ar][bn][jj]     + bh;   // hidden pre-activation
        float gg = acc[ar][bn + 2][jj] + bg;   // gate pre-activation
        float mabs = fabsf(gg);
        float em   = __expf(-mabs);
        float inv  = 1.f / (1.f + em);
        float z = (gg >= 0.f) ? inv : em * inv;       // sigmoid(gg)
        float a = (gg >= 0.f) ? em * inv : inv;       // sigmoid(-gg)
        float gf = (hh >= 0.f) ? (hh + 0.5f) : (1.f / (1.f + __expf(-hh)));
        float bb = z * gf;
        unsigned pk = ((unsigned)f2bf(bb) << 16) | (unsigned)f2bf(a);
        ab_out[(size_t)(row + jj) * E_ + e] = pk;
      }
    }
  }
}

// ---------------------------------------------------------------- GEMM2 (128x128, m97-style)
__global__ __launch_bounds__(256)
void gemm_bt(const short* __restrict__ A, const short* __restrict__ Bmat, int K,
             const float* __restrict__ bias, float* __restrict__ c_out, int ldc)
{
  __shared__ short As[128 * 64];
  __shared__ short Bs[128 * 64];
  const int tid  = threadIdx.x;
  const int lane = tid & 63;
  const int w    = tid >> 6;
  const int wr   = (w >> 1) * 64;
  const int wc   = (w & 1) * 64;

  const int nwg = gridDim.x * gridDim.y;
  const int lin = blockIdx.y * gridDim.x + blockIdx.x;
  const int nl  = (lin & 7) * (nwg >> 3) + (lin >> 3);
  const int brow = (nl / gridDim.x) * 128;
  const int bcol = (nl % gridDim.x) * 128;

  f32x4 acc[4][4];
  #pragma unroll
  for (int m = 0; m < 4; ++m)
    #pragma unroll
    for (int n = 0; n < 4; ++n) acc[m][n] = (f32x4){0.f, 0.f, 0.f, 0.f};

  const int srow = lane >> 3;
  const int scol = ((lane & 7) ^ srow) * 8;
  const int l15  = lane & 15;
  const int kh   = (lane >> 4) * 8;
  const int sw   = (l15 & 7) << 3;

  for (int kt = 0; kt < K; kt += 64) {
    #pragma unroll
    for (int i = 0; i < 4; ++i) {
      const int rr = (w * 4 + i) * 8 + srow;
      const short* ga = A    + (size_t)(brow + rr) * K + kt + scol;
      const short* gb = Bmat + (size_t)(bcol + rr) * K + kt + scol;
      STG(ga, As + (w * 4 + i) * 512);
      STG(gb, Bs + (w * 4 + i) * 512);
    }
    __syncthreads();
    #pragma unroll
    for (int kk = 0; kk < 64; kk += 32) {
      short8_t afr[4], bfr[4];
      #pragma unroll
      for (int m = 0; m < 4; ++m)
        afr[m] = *(const short8_t*)(As + (wr + m * 16 + l15) * 64 + ((kk + kh) ^ sw));
      #pragma unroll
      for (int n = 0; n < 4; ++n)
        bfr[n] = *(const short8_t*)(Bs + (wc + n * 16 + l15) * 64 + ((kk + kh) ^ sw));
      #pragma unroll
      for (int m = 0; m < 4; ++m)
        #pragma unroll
        for (int n = 0; n < 4; ++n)
          acc[m][n] = __builtin_amdgcn_mfma_f32_16x16x32_bf16(afr[m], bfr[n], acc[m][n], 0, 0, 0);
    }
    __syncthreads();
  }

  const int r4 = (lane >> 4) * 4;
  #pragma unroll
  for (int m = 0; m < 4; ++m) {
    #pragma unroll
    for (int n = 0; n < 4; ++n) {
      const int row = brow + wr + m * 16 + r4;
      const int col = bcol + wc + n * 16 + l15;
      #pragma unroll
      for (int j = 0; j < 4; ++j)
        c_out[(size_t)(row + j) * ldc + col] = acc[m][n][j] + bias[col];
    }
  }
}

// ---------------------------------------------------------------- scan (3-pass)
__global__ __launch_bounds__(256) void scan_chunk(const unsigned* __restrict__ ab,
                                                  float* __restrict__ Ac,
                                                  float* __restrict__ Bc){
  const int c = blockIdx.x;
  const int e = (blockIdx.y * 256 + threadIdx.x) * 4;
  const int b = blockIdx.z;
  size_t base = (((size_t)b * T_ + (size_t)c * CT_) * E_ + e) >> 2;  // uint4 index
  const uint4* abv = (const uint4*)ab;
  float A0=1.f,A1=1.f,A2=1.f,A3=1.f, H0=0.f,H1=0.f,H2=0.f,H3=0.f;
  #pragma unroll 4
  for (int t = 0; t < CT_; ++t) {
    uint4 wv = abv[base + (size_t)t * (E_ / 4)];
    float a0=bf2f(wv.x&0xffffu), b0=bf2f(wv.x>>16);
    float a1=bf2f(wv.y&0xffffu), b1=bf2f(wv.y>>16);
    float a2=bf2f(wv.z&0xffffu), b2=bf2f(wv.z>>16);
    float a3=bf2f(wv.w&0xffffu), b3=bf2f(wv.w>>16);
    H0=fmaf(a0,H0,b0); H1=fmaf(a1,H1,b1); H2=fmaf(a2,H2,b2); H3=fmaf(a3,H3,b3);
    A0*=a0; A1*=a1; A2*=a2; A3*=a3;
  }
  size_t ci = (((size_t)b * NC_ + c) * E_ + e) >> 2;
  ((float4*)Ac)[ci] = (float4){A0,A1,A2,A3};
  ((float4*)Bc)[ci] = (float4){H0,H1,H2,H3};
}

// Initial hidden state is 1.0 (reference pads log_values with 0 -> exp(0)=1).
__global__ __launch_bounds__(256) void scan_carry(const float* __restrict__ Ac,
                                                  const float* __restrict__ Bc,
                                                  float* __restrict__ Hc){
  int idx = blockIdx.x * 256 + threadIdx.x;   // 0..B_*E_-1
  int b = idx >> 11;                          // /E_
  int e = idx & (E_ - 1);
  float H = 1.f;                              // h_0 = 1 !
  for (int c = 0; c < NC_; ++c) {
    size_t ci = ((size_t)b * NC_ + c) * E_ + e;
    float A = Ac[ci], Bv = Bc[ci];
    Hc[ci] = H;                               // carry-in for chunk c
    H = fmaf(A, H, Bv);
  }
}

__global__ __launch_bounds__(256) void scan_final(const unsigned* __restrict__ ab,
                                                  const float* __restrict__ Hc,
                                                  short* __restrict__ h){
  const int c = blockIdx.x;
  const int e = (blockIdx.y * 256 + threadIdx.x) * 4;
  const int b = blockIdx.z;
  size_t base = (((size_t)b * T_ + (size_t)c * CT_) * E_ + e) >> 2;
  const uint4* abv = (const uint4*)ab;
  float4 Hv = ((const float4*)Hc)[(((size_t)b * NC_ + c) * E_ + e) >> 2];
  float H0=Hv.x, H1=Hv.y, H2=Hv.z, H3=Hv.w;
  short4* hv = (short4*)h;
  #pragma unroll 4
  for (int t = 0; t < CT_; ++t) {
    uint4 wv = abv[base + (size_t)t * (E_ / 4)];
    H0 = fmaf(bf2f(wv.x&0xffffu), H0, bf2f(wv.x>>16));
    H1 = fmaf(bf2f(wv.y&0xffffu), H1, bf2f(wv.y>>16));
    H2 = fmaf(bf2f(wv.z&0xffffu), H2, bf2f(wv.z>>16));
    H3 = fmaf(bf2f(wv.w&0xffffu), H3, bf2f(wv.w>>16));
    short4 o;
    o.x=(short)f2bf(H0); o.y=(short)f2bf(H1); o.z=(short)f2bf(H2); o.w=(short)f2bf(H3);
    hv[base + (size_t)t * (E_ / 4)] = o;
  }
}

// ---------------------------------------------------------------- launch
extern "C" void kernel_launch(void* const* d_in, const int* in_sizes, int n_in,
                              void* d_out, int out_size, void* d_ws, size_t ws_size,
                              hipStream_t stream)
{
  const float* x     = (const float*)d_in[0];
  const float* W_hg  = (const float*)d_in[1];
  const float* b_hg  = (const float*)d_in[2];
  const float* W_out = (const float*)d_in[3];
  const float* b_out = (const float*)d_in[4];
  float* out = (float*)d_out;

  char* p = (char*)d_ws;
  auto carve = [&](size_t bytes) -> char* {
    char* q = p; p += (bytes + 255) & ~(size_t)255; return q;
  };
  short*    xb   = (short*)   carve((size_t)M_ * K1_ * 2);   // 16.8 MB
  short*    Wp   = (short*)   carve((size_t)N1_ * K1_ * 2);  //  4.2 MB
  short*    Wo   = (short*)   carve((size_t)N2_ * K2_ * 2);  //  2.1 MB
  unsigned* ab   = (unsigned*)carve((size_t)M_ * E_ * 4);    // 134.2 MB
  short*    hbuf = (short*)   carve((size_t)M_ * E_ * 2);    // 67.1 MB
  float*    Ac   = (float*)   carve((size_t)B_ * NC_ * E_ * 4);
  float*    Bc   = (float*)   carve((size_t)B_ * NC_ * E_ * 4);
  float*    Hc   = (float*)   carve((size_t)B_ * NC_ * E_ * 4);

  conv_f32_bf16_x4<<<(M_ * K1_ / 4 + 255) / 256, 256, 0, stream>>>(x, xb, M_ * K1_ / 4);
  conv_whg<<<N1_, 128, 0, stream>>>(W_hg, Wp);
  conv_f32_bf16_x4<<<(N2_ * K2_ / 4 + 255) / 256, 256, 0, stream>>>(W_out, Wo, N2_ * K2_ / 4);

  gemm8p_ab<K1_><<<dim3(N1_ / 256, M_ / 256), 512, 0, stream>>>(xb, Wp, b_hg, ab);

  scan_chunk<<<dim3(NC_, E_ / 1024, B_), 256, 0, stream>>>(ab, Ac, Bc);
  scan_carry<<<(B_ * E_) / 256, 256, 0, stream>>>(Ac, Bc, Hc);
  scan_final<<<dim3(NC_, E_ / 1024, B_), 256, 0, stream>>>(ab, Hc, hbuf);

  gemm_bt<<<dim3(N2_ / 128, M_ / 128), 256, 0, stream>>>(hbuf, Wo, K2_, b_out, out, N2_);
}

// Round 8
// 300.141 us; speedup vs baseline: 1.4054x; 1.0031x over previous
//
#include <hip/hip_runtime.h>
#include <hip/hip_bf16.h>
#include <type_traits>

// Problem dims (fixed by setup_inputs)
#define B_   4
#define T_   4096
#define D_   512
#define E_   2048          // D_inner
#define M_   (B_*T_)       // 16384 rows
#define N1_  (2*E_)        // 4096 (reordered hidden/gate cols)
#define K1_  D_            // 512
#define N2_  D_            // 512
#define K2_  E_            // 2048
#define CT_  128           // scan chunk length
#define NC_  (T_/CT_)      // 32 chunks

typedef __attribute__((ext_vector_type(8))) short short8_t;
typedef __attribute__((ext_vector_type(4))) float f32x4;

__device__ inline unsigned short f2bf(float f){
  unsigned u = __float_as_uint(f);
  u += 0x7fffu + ((u >> 16) & 1u);      // RNE
  return (unsigned short)(u >> 16);
}
__device__ inline float bf2f(unsigned h){ return __uint_as_float(h << 16); }
__device__ inline float fast_rcp(float x){
  float r; asm("v_rcp_f32 %0, %1" : "=v"(r) : "v"(x)); return r;
}
__device__ inline unsigned pk_bf16(float lo, float hi){
  unsigned r; asm("v_cvt_pk_bf16_f32 %0, %1, %2" : "=v"(r) : "v"(lo), "v"(hi)); return r;
}

template<int I, int N, typename F>
__device__ __forceinline__ void sfor(F&& f){
  if constexpr (I < N) { f(std::integral_constant<int, I>{}); sfor<I + 1, N>(f); }
}

// ---------------------------------------------------------------- converts
__global__ __launch_bounds__(256) void conv_f32_bf16_x4(const float* __restrict__ in,
                                                        short* __restrict__ out, int n4){
  int i = blockIdx.x * 256 + threadIdx.x;
  if (i >= n4) return;
  float4 v = ((const float4*)in)[i];
  short4 o;
  o.x = (short)f2bf(v.x); o.y = (short)f2bf(v.y);
  o.z = (short)f2bf(v.z); o.w = (short)f2bf(v.w);
  ((short4*)out)[i] = o;
}

// W_hg [4096,512] -> Wp reordered: within each 64-col wave tile,
// cols 0..31 = hidden rows e_base..e_base+31, cols 32..63 = matching gate rows.
__global__ __launch_bounds__(128) void conv_whg(const float* __restrict__ W,
                                                short* __restrict__ Wp){
  int r = blockIdx.x;                                  // 0..4095
  int e = ((r >> 6) << 5) + (r & 31);
  int orig = e + ((r >> 5) & 1) * E_;
  float4 v = ((const float4*)(W + (size_t)orig * K1_))[threadIdx.x];
  short4 o;
  o.x = (short)f2bf(v.x); o.y = (short)f2bf(v.y);
  o.z = (short)f2bf(v.z); o.w = (short)f2bf(v.w);
  ((short4*)(Wp + (size_t)r * K1_))[threadIdx.x] = o;
}

// ---------------------------------------------------------------- GEMM (B^T layout)
// 128x128 tile, BK=64, 4 waves, double-buffered LDS (64 KiB -> 2 blocks/CU),
// ONE barrier per K-step (guide T3-minimum template): stage(t+1 -> buf^1)
// issued BEFORE compute(buf); __syncthreads()'s vmcnt(0)-drain lands after
// MFMA covered the load latency (drain-at-barrier verified by R2 passing).
// XOR-swizzle (colbyte ^= (row&7)<<4) via pre-swizzled global src (linear LDS
// dest) + swizzled ds_read. K fully unrolled; kt folded into the POINTER
// expression (constexpr), builtin offset arg stays 0 (HW-verified form only —
// R4's offset!=0 form corrupted LDS).
template<int EPI, int KK>
__global__ __launch_bounds__(256, 2)
void gemm_db(const short* __restrict__ A, const short* __restrict__ Bmat,
             const float* __restrict__ bias,
             unsigned* __restrict__ ab_out,
             float* __restrict__ c_out, int ldc)
{
  __shared__ short As[2][128 * 64];
  __shared__ short Bs[2][128 * 64];
  constexpr int NT = KK / 64;

  const int tid  = threadIdx.x;
  const int lane = tid & 63;
  const int w    = tid >> 6;
  const int wr   = (w >> 1) * 64;
  const int wc   = (w & 1) * 64;

  // bijective XCD-aware block swizzle (nwg % 8 == 0 for both GEMMs)
  const int nwg = gridDim.x * gridDim.y;
  const int lin = blockIdx.y * gridDim.x + blockIdx.x;
  const int nl  = (lin & 7) * (nwg >> 3) + (lin >> 3);
  const int brow = (nl / gridDim.x) * 128;
  const int bcol = (nl % gridDim.x) * 128;

  f32x4 acc[4][4];
  #pragma unroll
  for (int m = 0; m < 4; ++m)
    #pragma unroll
    for (int n = 0; n < 4; ++n) acc[m][n] = (f32x4){0.f, 0.f, 0.f, 0.f};

  const int srow = lane >> 3;
  const int scol = ((lane & 7) ^ srow) * 8;   // pre-swizzled global col (shorts)
  const int l15  = lane & 15;
  const int kh   = (lane >> 4) * 8;
  const int sw   = (l15 & 7) << 3;            // ds_read XOR (shorts)

  // 8 base addresses (4 per matrix); kt folded in as constexpr displacement
  const short* ga[4]; const short* gb[4];
  #pragma unroll
  for (int i = 0; i < 4; ++i) {
    const int rr = (w * 4 + i) * 8 + srow;
    ga[i] = A    + (size_t)(brow + rr) * KK + scol;
    gb[i] = Bmat + (size_t)(bcol + rr) * KK + scol;
  }

  auto stage = [&](auto CUR, auto TT) {
    constexpr int cb = decltype(CUR)::value;
    constexpr int kt = decltype(TT)::value * 64;     // shorts
    #pragma unroll
    for (int i = 0; i < 4; ++i) {
      __builtin_amdgcn_global_load_lds(
          (const __attribute__((address_space(1))) void*)(ga[i] + kt),
          (__attribute__((address_space(3))) void*)&As[cb][(w * 4 + i) * 512], 16, 0, 0);
      __builtin_amdgcn_global_load_lds(
          (const __attribute__((address_space(1))) void*)(gb[i] + kt),
          (__attribute__((address_space(3))) void*)&Bs[cb][(w * 4 + i) * 512], 16, 0, 0);
    }
  };
  auto comp = [&](auto CUR) {
    constexpr int cb = decltype(CUR)::value;
    #pragma unroll
    for (int kk = 0; kk < 64; kk += 32) {
      short8_t afr[4], bfr[4];
      #pragma unroll
      for (int m = 0; m < 4; ++m)
        afr[m] = *(const short8_t*)&As[cb][(wr + m * 16 + l15) * 64 + ((kk + kh) ^ sw)];
      #pragma unroll
      for (int n = 0; n < 4; ++n)
        bfr[n] = *(const short8_t*)&Bs[cb][(wc + n * 16 + l15) * 64 + ((kk + kh) ^ sw)];
      #pragma unroll
      for (int m = 0; m < 4; ++m)
        #pragma unroll
        for (int n = 0; n < 4; ++n)
          acc[m][n] = __builtin_amdgcn_mfma_f32_16x16x32_bf16(afr[m], bfr[n], acc[m][n], 0, 0, 0);
    }
  };

  stage(std::integral_constant<int, 0>{}, std::integral_constant<int, 0>{});
  __syncthreads();

  sfor<0, NT>([&](auto TT) {
    constexpr int t   = decltype(TT)::value;
    constexpr int cur = t & 1;
    if constexpr (t + 1 < NT)
      stage(std::integral_constant<int, cur ^ 1>{}, std::integral_constant<int, t + 1>{});
    comp(std::integral_constant<int, cur>{});
    if constexpr (t + 1 < NT) __syncthreads();
  });

  const int r4 = (lane >> 4) * 4;
  if constexpr (EPI == 0) {
    // cols [wc..wc+31] = hidden(e), [wc+32..wc+63] = gate(e): same lane holds both
    const int ebase = (bcol + wc) >> 1;
    #pragma unroll
    for (int m = 0; m < 4; ++m) {
      const int row = brow + wr + m * 16 + r4;
      #pragma unroll
      for (int n = 0; n < 2; ++n) {
        const int e = ebase + n * 16 + l15;
        const float bh = bias[e];
        const float bg = bias[E_ + e];
        #pragma unroll
        for (int j = 0; j < 4; ++j) {
          float hh = acc[m][n][j]     + bh;   // hidden pre-activation
          float gg = acc[m][n + 2][j] + bg;   // gate pre-activation
          float r  = fast_rcp(1.f + __expf(-fabsf(gg)));
          float z  = (gg >= 0.f) ? r : 1.f - r;   // sigmoid(gg)
          float a  = 1.f - z;                     // sigmoid(-gg)
          float gf = (hh >= 0.f) ? (hh + 0.5f) : fast_rcp(1.f + __expf(-hh));
          float bb = z * gf;
          ab_out[(size_t)(row + j) * E_ + e] = pk_bf16(a, bb);
        }
      }
    }
  } else {
    #pragma unroll
    for (int m = 0; m < 4; ++m) {
      #pragma unroll
      for (int n = 0; n < 4; ++n) {
        const int row = brow + wr + m * 16 + r4;
        const int col = bcol + wc + n * 16 + l15;
        #pragma unroll
        for (int j = 0; j < 4; ++j)
          c_out[(size_t)(row + j) * ldc + col] = acc[m][n][j] + bias[col];
      }
    }
  }
}

// ---------------------------------------------------------------- scan (3-pass)
__global__ __launch_bounds__(256) void scan_chunk(const unsigned* __restrict__ ab,
                                                  float* __restrict__ Ac,
                                                  float* __restrict__ Bc){
  const int c = blockIdx.x;
  const int e = (blockIdx.y * 256 + threadIdx.x) * 4;
  const int b = blockIdx.z;
  size_t base = (((size_t)b * T_ + (size_t)c * CT_) * E_ + e) >> 2;  // uint4 index
  const uint4* abv = (const uint4*)ab;
  float A0=1.f,A1=1.f,A2=1.f,A3=1.f, H0=0.f,H1=0.f,H2=0.f,H3=0.f;
  #pragma unroll 4
  for (int t = 0; t < CT_; ++t) {
    uint4 wv = abv[base + (size_t)t * (E_ / 4)];
    float a0=bf2f(wv.x&0xffffu), b0=bf2f(wv.x>>16);
    float a1=bf2f(wv.y&0xffffu), b1=bf2f(wv.y>>16);
    float a2=bf2f(wv.z&0xffffu), b2=bf2f(wv.z>>16);
    float a3=bf2f(wv.w&0xffffu), b3=bf2f(wv.w>>16);
    H0=fmaf(a0,H0,b0); H1=fmaf(a1,H1,b1); H2=fmaf(a2,H2,b2); H3=fmaf(a3,H3,b3);
    A0*=a0; A1*=a1; A2*=a2; A3*=a3;
  }
  size_t ci = (((size_t)b * NC_ + c) * E_ + e) >> 2;
  ((float4*)Ac)[ci] = (float4){A0,A1,A2,A3};
  ((float4*)Bc)[ci] = (float4){H0,H1,H2,H3};
}

// Initial hidden state is 1.0 (reference pads log_values with 0 -> exp(0)=1).
__global__ __launch_bounds__(256) void scan_carry(const float* __restrict__ Ac,
                                                  const float* __restrict__ Bc,
                                                  float* __restrict__ Hc){
  int idx = blockIdx.x * 256 + threadIdx.x;   // 0..B_*E_-1
  int b = idx >> 11;                          // /E_
  int e = idx & (E_ - 1);
  float H = 1.f;                              // h_0 = 1 !
  for (int c = 0; c < NC_; ++c) {
    size_t ci = ((size_t)b * NC_ + c) * E_ + e;
    float A = Ac[ci], Bv = Bc[ci];
    Hc[ci] = H;                               // carry-in for chunk c
    H = fmaf(A, H, Bv);
  }
}

__global__ __launch_bounds__(256) void scan_final(const unsigned* __restrict__ ab,
                                                  const float* __restrict__ Hc,
                                                  short* __restrict__ h){
  const int c = blockIdx.x;
  const int e = (blockIdx.y * 256 + threadIdx.x) * 4;
  const int b = blockIdx.z;
  size_t base = (((size_t)b * T_ + (size_t)c * CT_) * E_ + e) >> 2;
  const uint4* abv = (const uint4*)ab;
  float4 Hv = ((const float4*)Hc)[(((size_t)b * NC_ + c) * E_ + e) >> 2];
  float H0=Hv.x, H1=Hv.y, H2=Hv.z, H3=Hv.w;
  short4* hv = (short4*)h;
  #pragma unroll 4
  for (int t = 0; t < CT_; ++t) {
    uint4 wv = abv[base + (size_t)t * (E_ / 4)];
    H0 = fmaf(bf2f(wv.x&0xffffu), H0, bf2f(wv.x>>16));
    H1 = fmaf(bf2f(wv.y&0xffffu), H1, bf2f(wv.y>>16));
    H2 = fmaf(bf2f(wv.z&0xffffu), H2, bf2f(wv.z>>16));
    H3 = fmaf(bf2f(wv.w&0xffffu), H3, bf2f(wv.w>>16));
    short4 o;
    o.x=(short)f2bf(H0); o.y=(short)f2bf(H1); o.z=(short)f2bf(H2); o.w=(short)f2bf(H3);
    hv[base + (size_t)t * (E_ / 4)] = o;
  }
}

// ---------------------------------------------------------------- launch
extern "C" void kernel_launch(void* const* d_in, const int* in_sizes, int n_in,
                              void* d_out, int out_size, void* d_ws, size_t ws_size,
                              hipStream_t stream)
{
  const float* x     = (const float*)d_in[0];
  const float* W_hg  = (const float*)d_in[1];
  const float* b_hg  = (const float*)d_in[2];
  const float* W_out = (const float*)d_in[3];
  const float* b_out = (const float*)d_in[4];
  float* out = (float*)d_out;

  char* p = (char*)d_ws;
  auto carve = [&](size_t bytes) -> char* {
    char* q = p; p += (bytes + 255) & ~(size_t)255; return q;
  };
  short*    xb   = (short*)   carve((size_t)M_ * K1_ * 2);   // 16.8 MB
  short*    Wp   = (short*)   carve((size_t)N1_ * K1_ * 2);  //  4.2 MB
  short*    Wo   = (short*)   carve((size_t)N2_ * K2_ * 2);  //  2.1 MB
  unsigned* ab   = (unsigned*)carve((size_t)M_ * E_ * 4);    // 134.2 MB
  short*    hbuf = (short*)   carve((size_t)M_ * E_ * 2);    // 67.1 MB
  float*    Ac   = (float*)   carve((size_t)B_ * NC_ * E_ * 4);
  float*    Bc   = (float*)   carve((size_t)B_ * NC_ * E_ * 4);
  float*    Hc   = (float*)   carve((size_t)B_ * NC_ * E_ * 4);

  conv_f32_bf16_x4<<<(M_ * K1_ / 4 + 255) / 256, 256, 0, stream>>>(x, xb, M_ * K1_ / 4);
  conv_whg<<<N1_, 128, 0, stream>>>(W_hg, Wp);
  conv_f32_bf16_x4<<<(N2_ * K2_ / 4 + 255) / 256, 256, 0, stream>>>(W_out, Wo, N2_ * K2_ / 4);

  gemm_db<0, K1_><<<dim3(N1_ / 128, M_ / 128), 256, 0, stream>>>(xb, Wp, b_hg, ab, nullptr, 0);

  scan_chunk<<<dim3(NC_, E_ / 1024, B_), 256, 0, stream>>>(ab, Ac, Bc);
  scan_carry<<<(B_ * E_) / 256, 256, 0, stream>>>(Ac, Bc, Hc);
  scan_final<<<dim3(NC_, E_ / 1024, B_), 256, 0, stream>>>(ab, Hc, hbuf);

  gemm_db<1, K2_><<<dim3(N2_ / 128, M_ / 128), 256, 0, stream>>>(hbuf, Wo, b_out, nullptr, out, N2_);
}